// Round 4
// baseline (307.763 us; speedup 1.0000x reference)
//
#include <hip/hip_runtime.h>

// PhyGRUResidualCell: B=2097152 rows, state=7 (3 phys + 4 latent), u=3.
// One thread per row; all weights are wave-uniform (s_load + v_fmac v,s,v).
// fp32 VALU-bound: ~1665 FMA + ~167 activations per row.

#define DT_C 0.01f
#define NROWS 2097152
#define LOG2E 1.44269504088896340736f

__device__ __forceinline__ float fast_exp(float x) {
    return __builtin_amdgcn_exp2f(x * LOG2E);
}
// tanh(x) = 1 - 2/(1 + e^{2x}); saturates correctly for |x| large.
__device__ __forceinline__ float fast_tanh(float x) {
    float e = __builtin_amdgcn_exp2f(x * (2.0f * LOG2E));
    return 1.0f - 2.0f * __builtin_amdgcn_rcpf(1.0f + e);
}
__device__ __forceinline__ float fast_sigmoid(float x) {
    float e = __builtin_amdgcn_exp2f(-x * LOG2E);
    return __builtin_amdgcn_rcpf(1.0f + e);
}

__global__ __launch_bounds__(256) void phygru_kernel(
    const float* __restrict__ state, const float* __restrict__ u,
    const float* __restrict__ A,     const float* __restrict__ Bm,
    const float* __restrict__ C,     const float* __restrict__ Wz,
    const float* __restrict__ bz,    const float* __restrict__ W1,
    const float* __restrict__ b1,    const float* __restrict__ W2,
    const float* __restrict__ b2,    const float* __restrict__ Wb1,
    const float* __restrict__ bb1,   const float* __restrict__ Wb2,
    const float* __restrict__ bb2,   float* __restrict__ out)
{
    const int row = blockIdx.x * blockDim.x + threadIdx.x;

    // ---- load row (10 floats) ----
    float st[7];
    #pragma unroll
    for (int i = 0; i < 7; ++i) st[i] = state[row * 7 + i];
    float uu[3];
    #pragma unroll
    for (int i = 0; i < 3; ++i) uu[i] = u[row * 3 + i];

    // su = [state(7), u(3)]
    float su[10];
    #pragma unroll
    for (int i = 0; i < 7; ++i) su[i] = st[i];
    #pragma unroll
    for (int i = 0; i < 3; ++i) su[7 + i] = uu[i];

    // ---- physics: s_dot = A s + Bm u ; y_phys = C s ; sp = s + DT*s_dot ----
    float sp[3], yp[3];
    #pragma unroll
    for (int i = 0; i < 3; ++i) {
        float sd = 0.0f;
        #pragma unroll
        for (int j = 0; j < 3; ++j) sd = fmaf(A[i * 3 + j], st[j], sd);
        #pragma unroll
        for (int j = 0; j < 3; ++j) sd = fmaf(Bm[i * 3 + j], uu[j], sd);
        float y = 0.0f;
        #pragma unroll
        for (int j = 0; j < 3; ++j) y = fmaf(C[i * 3 + j], st[j], y);
        sp[i] = fmaf(DT_C, sd, st[i]);
        yp[i] = y;
    }

    // ---- latent MLP: ld = W2 * tanh(W1*su + b1) + b2 (fused, no h1 array) ----
    float ld[4] = { b2[0], b2[1], b2[2], b2[3] };
    #pragma unroll
    for (int h = 0; h < 64; ++h) {
        float a = b1[h];
        #pragma unroll
        for (int i = 0; i < 10; ++i) a = fmaf(W1[h * 10 + i], su[i], a);
        float t = fast_tanh(a);
        #pragma unroll
        for (int k = 0; k < 4; ++k) ld[k] = fmaf(W2[k * 64 + h], t, ld[k]);
    }
    float ln[4];
    #pragma unroll
    for (int k = 0; k < 4; ++k) ln[k] = fmaf(DT_C, ld[k], st[3 + k]);

    // ---- gate: z = sigmoid(Wz*su + bz); ns = st + z*(cand - st) ----
    float ns[7];
    #pragma unroll
    for (int j = 0; j < 7; ++j) {
        float a = bz[j];
        #pragma unroll
        for (int i = 0; i < 10; ++i) a = fmaf(Wz[j * 10 + i], su[i], a);
        float z = fast_sigmoid(a);
        float cand = (j < 3) ? sp[j] : ln[j - 3];
        ns[j] = fmaf(z, cand - st[j], st[j]);
    }

    // ---- branch residuals: r[k] = Wb2[k] . tanh(Wb1[k]*bi + bb1[k]) ----
    float bi[6] = { st[0], st[1], st[2], uu[0], uu[1], uu[2] };
    float res[3];
    #pragma unroll
    for (int k = 0; k < 3; ++k) {
        float r = bb2[k];
        #pragma unroll
        for (int h = 0; h < 32; ++h) {
            float a = bb1[k * 32 + h];
            #pragma unroll
            for (int i = 0; i < 6; ++i)
                a = fmaf(Wb1[(k * 32 + h) * 6 + i], bi[i], a);
            r = fmaf(Wb2[k * 32 + h], fast_tanh(a), r);
        }
        res[k] = r;
    }

    // ---- stores: next_state (B x 7) then y (B x 3) ----
    #pragma unroll
    for (int j = 0; j < 7; ++j) out[row * 7 + j] = ns[j];
    float* yout = out + (size_t)NROWS * 7;
    #pragma unroll
    for (int k = 0; k < 3; ++k) yout[row * 3 + k] = yp[k] + res[k];
}

extern "C" void kernel_launch(void* const* d_in, const int* in_sizes, int n_in,
                              void* d_out, int out_size, void* d_ws, size_t ws_size,
                              hipStream_t stream) {
    const float* state = (const float*)d_in[0];
    const float* u     = (const float*)d_in[1];
    const float* A     = (const float*)d_in[2];
    const float* Bm    = (const float*)d_in[3];
    const float* C     = (const float*)d_in[4];
    const float* Wz    = (const float*)d_in[5];
    const float* bz    = (const float*)d_in[6];
    const float* W1    = (const float*)d_in[7];
    const float* b1    = (const float*)d_in[8];
    const float* W2    = (const float*)d_in[9];
    const float* b2    = (const float*)d_in[10];
    const float* Wb1   = (const float*)d_in[11];
    const float* bb1   = (const float*)d_in[12];
    const float* Wb2   = (const float*)d_in[13];
    const float* bb2   = (const float*)d_in[14];
    float* out = (float*)d_out;

    dim3 grid(NROWS / 256), block(256);
    phygru_kernel<<<grid, block, 0, stream>>>(
        state, u, A, Bm, C, Wz, bz, W1, b1, W2, b2, Wb1, bb1, Wb2, bb2, out);
}

// Round 9
// 259.664 us; speedup vs baseline: 1.1852x; 1.1852x over previous
//
#include <hip/hip_runtime.h>
#include <stdint.h>

// PhyGRUResidualCell: B=2097152 rows, state=7 (3 phys + 4 latent), u=3.
// Round 8 (= R5 type-fixed): v_dot2_f32_f16 (2 MAC/inst) for all matvecs +
// prep kernel packing weights to half2 with activation scales pre-folded
// (tanh: x*2log2e, sigmoid: -x*log2e).
// h2 must be __fp16 ext_vector(2): cvt_pkrtz/fdot2 builtins use V2h (__fp16).
// Baseline R4: 193us/dispatch, VALUBusy 88%, HBM 8% -> pure VALU-issue-bound.

#define DT_C 0.01f
#define NROWS 2097152
#define LOG2E 1.4426950408889634f
#define S2L   2.8853901617779268f   /* 2*log2(e) */

typedef __fp16 h2 __attribute__((ext_vector_type(2)));

__device__ __forceinline__ h2 pkrtz(float a, float b) {
    return __builtin_amdgcn_cvt_pkrtz(a, b);
}

#if __has_builtin(__builtin_amdgcn_fdot2)
__device__ __forceinline__ float fdot2(h2 a, h2 b, float c) {
    return __builtin_amdgcn_fdot2(a, b, c, false);
}
#else
__device__ __forceinline__ float fdot2(h2 a, h2 b, float c) {
    return fmaf((float)a[0], (float)b[0], fmaf((float)a[1], (float)b[1], c));
}
#endif

// input already scaled by 2*log2e: tanh = 1 - 2/(1+2^xs)
__device__ __forceinline__ float tanh_pre(float xs) {
    float e = __builtin_amdgcn_exp2f(xs);
    return fmaf(-2.0f, __builtin_amdgcn_rcpf(1.0f + e), 1.0f);
}
// input already scaled by -log2e: sigmoid = 1/(1+2^xs)
__device__ __forceinline__ float sigmoid_pre(float xs) {
    float e = __builtin_amdgcn_exp2f(xs);
    return __builtin_amdgcn_rcpf(1.0f + e);
}

// ---- d_ws layout (uint32 word offsets) ----
#define W1P_OFF   0      /* 64x5  h2 : W1 row pairs, *S2L          */
#define WZP_OFF   320    /* 7x5   h2 : Wz row pairs, *(-LOG2E)     */
#define WB1P_OFF  355    /* 96x3  h2 : Wb1 row pairs, *S2L         */
#define W2P_OFF   643    /* 4x32  h2 : W2 h-pairs, unscaled        */
#define PHYSP_OFF 771    /* 3x3   h2 : (A|Bm) row pairs            */
#define CP_OFF    780    /* 3x2   h2 : C row pairs (pad 0)         */
#define B1S_OFF   786    /* 64 f32 : b1*S2L                        */
#define BZS_OFF   850    /* 7  f32 : bz*(-LOG2E)                   */
#define BB1S_OFF  857    /* 96 f32 : bb1*S2L                       */
/* total 953 words (<4KB) */

__device__ __forceinline__ uint32_t pack2(float a, float b) {
    h2 v = pkrtz(a, b);
    uint32_t u; __builtin_memcpy(&u, &v, 4); return u;
}

__global__ void prep_kernel(const float* __restrict__ A, const float* __restrict__ Bm,
                            const float* __restrict__ C, const float* __restrict__ Wz,
                            const float* __restrict__ bz, const float* __restrict__ W1,
                            const float* __restrict__ b1, const float* __restrict__ Wb1,
                            const float* __restrict__ bb1, const float* __restrict__ W2,
                            uint32_t* __restrict__ ws)
{
    const int tid = blockIdx.x * blockDim.x + threadIdx.x;
    const int nt = gridDim.x * blockDim.x;
    float* wsf = (float*)ws;

    for (int i = tid; i < 320; i += nt) {          // W1 pairs *S2L
        int h = i / 5, j = i % 5;
        ws[W1P_OFF + i] = pack2(W1[h*10 + 2*j] * S2L, W1[h*10 + 2*j + 1] * S2L);
    }
    for (int i = tid; i < 35; i += nt) {           // Wz pairs *(-L)
        int r = i / 5, j = i % 5;
        ws[WZP_OFF + i] = pack2(Wz[r*10 + 2*j] * -LOG2E, Wz[r*10 + 2*j + 1] * -LOG2E);
    }
    for (int i = tid; i < 288; i += nt) {          // Wb1 pairs *S2L
        int row = i / 3, j = i % 3;
        ws[WB1P_OFF + i] = pack2(Wb1[row*6 + 2*j] * S2L, Wb1[row*6 + 2*j + 1] * S2L);
    }
    for (int i = tid; i < 128; i += nt) {          // W2 h-pairs
        int k = i / 32, j = i % 32;
        ws[W2P_OFF + i] = pack2(W2[k*64 + 2*j], W2[k*64 + 2*j + 1]);
    }
    for (int i = tid; i < 9; i += nt) {            // (A|Bm) pairs vs bi=(s0,s1|s2,u0|u1,u2)
        int r = i / 3, j = i % 3;
        float a, b;
        if (j == 0) { a = A[r*3+0];  b = A[r*3+1];  }
        else if (j == 1) { a = A[r*3+2];  b = Bm[r*3+0]; }
        else { a = Bm[r*3+1]; b = Bm[r*3+2]; }
        ws[PHYSP_OFF + i] = pack2(a, b);
    }
    for (int i = tid; i < 6; i += nt) {            // C pairs (pad 0 vs u0)
        int r = i / 2, j = i % 2;
        float a = (j == 0) ? C[r*3+0] : C[r*3+2];
        float b = (j == 0) ? C[r*3+1] : 0.0f;
        ws[CP_OFF + i] = pack2(a, b);
    }
    for (int i = tid; i < 64; i += nt) wsf[B1S_OFF + i] = b1[i] * S2L;
    for (int i = tid; i < 7;  i += nt) wsf[BZS_OFF + i] = bz[i] * -LOG2E;
    for (int i = tid; i < 96; i += nt) wsf[BB1S_OFF + i] = bb1[i] * S2L;
}

__global__ __launch_bounds__(256) void phygru_kernel(
    const float* __restrict__ state, const float* __restrict__ u,
    const uint32_t* __restrict__ ws, const float* __restrict__ b2,
    const float* __restrict__ Wb2,   const float* __restrict__ bb2,
    float* __restrict__ out)
{
    const int row = blockIdx.x * blockDim.x + threadIdx.x;

    const h2* W1p  = (const h2*)(ws + W1P_OFF);
    const h2* Wzp  = (const h2*)(ws + WZP_OFF);
    const h2* Wb1p = (const h2*)(ws + WB1P_OFF);
    const h2* W2p  = (const h2*)(ws + W2P_OFF);
    const h2* Pp   = (const h2*)(ws + PHYSP_OFF);
    const h2* Cp   = (const h2*)(ws + CP_OFF);
    const float* wsf  = (const float*)ws;
    const float* b1s  = wsf + B1S_OFF;
    const float* bzs  = wsf + BZS_OFF;
    const float* bb1s = wsf + BB1S_OFF;

    // ---- load row ----
    float st[7];
    #pragma unroll
    for (int i = 0; i < 7; ++i) st[i] = state[row * 7 + i];
    float uu[3];
    #pragma unroll
    for (int i = 0; i < 3; ++i) uu[i] = u[row * 3 + i];

    // packed su = [st(7), u(3)] as 5 half2; bi = [st(3), u(3)] as 3 half2
    h2 suh[5];
    suh[0] = pkrtz(st[0], st[1]);
    suh[1] = pkrtz(st[2], st[3]);
    suh[2] = pkrtz(st[4], st[5]);
    suh[3] = pkrtz(st[6], uu[0]);
    suh[4] = pkrtz(uu[1], uu[2]);
    h2 bih[3];
    bih[0] = suh[0];
    bih[1] = pkrtz(st[2], uu[0]);
    bih[2] = suh[4];

    // ---- physics ----
    float sp[3], yp[3];
    #pragma unroll
    for (int r = 0; r < 3; ++r) {
        float sd = fdot2(Pp[r*3+0], bih[0],
                   fdot2(Pp[r*3+1], bih[1],
                   fdot2(Pp[r*3+2], bih[2], 0.0f)));
        sp[r] = fmaf(DT_C, sd, st[r]);
        yp[r] = fdot2(Cp[r*2+0], bih[0], fdot2(Cp[r*2+1], bih[1], 0.0f));
    }

    // ---- latent MLP (h in pairs; tanh inputs pre-scaled by S2L) ----
    float ld0 = b2[0], ld1 = b2[1], ld2 = b2[2], ld3 = b2[3];
    #pragma unroll
    for (int hp = 0; hp < 32; ++hp) {
        const int h0 = 2 * hp, h1 = 2 * hp + 1;
        float a0 = b1s[h0], a1 = b1s[h1];
        #pragma unroll
        for (int j = 0; j < 5; ++j) {
            a0 = fdot2(W1p[h0*5 + j], suh[j], a0);
            a1 = fdot2(W1p[h1*5 + j], suh[j], a1);
        }
        h2 th = pkrtz(tanh_pre(a0), tanh_pre(a1));
        ld0 = fdot2(W2p[0*32 + hp], th, ld0);
        ld1 = fdot2(W2p[1*32 + hp], th, ld1);
        ld2 = fdot2(W2p[2*32 + hp], th, ld2);
        ld3 = fdot2(W2p[3*32 + hp], th, ld3);
    }
    float ln[4];
    ln[0] = fmaf(DT_C, ld0, st[3]);
    ln[1] = fmaf(DT_C, ld1, st[4]);
    ln[2] = fmaf(DT_C, ld2, st[5]);
    ln[3] = fmaf(DT_C, ld3, st[6]);

    // ---- gate (sigmoid inputs pre-scaled by -LOG2E) ----
    float ns[7];
    #pragma unroll
    for (int j = 0; j < 7; ++j) {
        float a = bzs[j];
        #pragma unroll
        for (int i = 0; i < 5; ++i) a = fdot2(Wzp[j*5 + i], suh[i], a);
        float z = sigmoid_pre(a);
        float cand = (j < 3) ? sp[j] : ln[j - 3];
        ns[j] = fmaf(z, cand - st[j], st[j]);
    }

    // ---- branch residuals (tanh inputs pre-scaled by S2L) ----
    float res[3];
    #pragma unroll
    for (int k = 0; k < 3; ++k) {
        float r = bb2[k];
        #pragma unroll
        for (int h = 0; h < 32; ++h) {
            float a = bb1s[k*32 + h];
            #pragma unroll
            for (int j = 0; j < 3; ++j)
                a = fdot2(Wb1p[(k*32 + h)*3 + j], bih[j], a);
            r = fmaf(Wb2[k*32 + h], tanh_pre(a), r);
        }
        res[k] = r;
    }

    // ---- stores ----
    #pragma unroll
    for (int j = 0; j < 7; ++j) out[row * 7 + j] = ns[j];
    float* yout = out + (size_t)NROWS * 7;
    #pragma unroll
    for (int k = 0; k < 3; ++k) yout[row * 3 + k] = yp[k] + res[k];
}

extern "C" void kernel_launch(void* const* d_in, const int* in_sizes, int n_in,
                              void* d_out, int out_size, void* d_ws, size_t ws_size,
                              hipStream_t stream) {
    const float* state = (const float*)d_in[0];
    const float* u     = (const float*)d_in[1];
    const float* A     = (const float*)d_in[2];
    const float* Bm    = (const float*)d_in[3];
    const float* C     = (const float*)d_in[4];
    const float* Wz    = (const float*)d_in[5];
    const float* bz    = (const float*)d_in[6];
    const float* W1    = (const float*)d_in[7];
    const float* b1    = (const float*)d_in[8];
    const float* W2    = (const float*)d_in[9];
    const float* b2    = (const float*)d_in[10];
    const float* Wb1   = (const float*)d_in[11];
    const float* bb1   = (const float*)d_in[12];
    const float* Wb2   = (const float*)d_in[13];
    const float* bb2   = (const float*)d_in[14];
    float* out = (float*)d_out;
    uint32_t* ws = (uint32_t*)d_ws;

    prep_kernel<<<4, 256, 0, stream>>>(A, Bm, C, Wz, bz, W1, b1, Wb1, bb1, W2, ws);
    phygru_kernel<<<NROWS / 256, 256, 0, stream>>>(state, u, ws, b2, Wb2, bb2, out);
}

// Round 14
// 250.086 us; speedup vs baseline: 1.2306x; 1.0383x over previous
//
#include <hip/hip_runtime.h>
#include <stdint.h>

// PhyGRUResidualCell: B=2097152 rows, state=7 (3 phys + 4 latent), u=3.
// R10: R9 (dot2 matvecs) + LDS PWL tanh table (512x{val,slope} over [-8,8]).
// Table coordinate folded into weights: W1,Wb1 *32 (=1/h, exact), Wz *16
// (sigmoid = 0.5+0.5*tanh(y/2)), biases *scale+256. Activation = med3 +
// fract + cvt + lshl + ds_read_b64 + fma  (~10 VALU cy) vs exp2+rcp (~36 cy).
// R9: 135us, VALUBusy 86%, HBM 12%; ~70% of cycles in 334 transcendentals.

#define DT_C  0.01f
#define NROWS 2097152
#define LOG2E 1.4426950408889634f
#define TBL_H   0.03125f   /* 16/512 */
#define INV_H   32.0f
#define INV_H2  16.0f      /* for sigmoid: tanh(y/2) */
#define TBL_C   256.0f
#define TBL_MAX 511.999f

typedef __fp16 h2 __attribute__((ext_vector_type(2)));

__device__ __forceinline__ h2 pkrtz(float a, float b) {
    return __builtin_amdgcn_cvt_pkrtz(a, b);
}

#if __has_builtin(__builtin_amdgcn_fdot2)
__device__ __forceinline__ float fdot2(h2 a, h2 b, float c) {
    return __builtin_amdgcn_fdot2(a, b, c, false);
}
#else
__device__ __forceinline__ float fdot2(h2 a, h2 b, float c) {
    return fmaf((float)a[0], (float)b[0], fmaf((float)a[1], (float)b[1], c));
}
#endif

// accurate tanh for table build only
__device__ __forceinline__ float tanh_ref(float x) {
    float e = __builtin_amdgcn_exp2f(x * (2.0f * LOG2E));
    return 1.0f - 2.0f * __builtin_amdgcn_rcpf(1.0f + e);
}

__device__ __forceinline__ float fract_f(float x) {
#if __has_builtin(__builtin_amdgcn_fractf)
    return __builtin_amdgcn_fractf(x);
#else
    return x - truncf(x);
#endif
}

__device__ __forceinline__ float med3f(float x, float lo, float hi) {
#if __has_builtin(__builtin_amdgcn_fmed3f)
    return __builtin_amdgcn_fmed3f(x, lo, hi);
#else
    return fminf(fmaxf(x, lo), hi);
#endif
}

// t is already in table units: t = a*INV_H + TBL_C (folded into weights/bias)
__device__ __forceinline__ float tanh_lut(float t, const float2* lut) {
    float tc = med3f(t, 0.0f, TBL_MAX);
    float fr = fract_f(tc);
    int   i  = (int)tc;
    float2 e = lut[i];
    return fmaf(e.y, fr, e.x);
}

// ---- d_ws layout (uint32 word offsets) ----
#define W1P_OFF   0      /* 64x5  h2 : W1 row pairs, *INV_H        */
#define WZP_OFF   320    /* 7x5   h2 : Wz row pairs, *INV_H2       */
#define WB1P_OFF  355    /* 96x3  h2 : Wb1 row pairs, *INV_H       */
#define W2P_OFF   643    /* 4x32  h2 : W2 h-pairs, unscaled        */
#define PHYSP_OFF 771    /* 3x3   h2 : (A|Bm) row pairs            */
#define CP_OFF    780    /* 3x2   h2 : C row pairs (pad 0)         */
#define B1S_OFF   786    /* 64 f32 : b1*INV_H + 256                */
#define BZS_OFF   850    /* 7  f32 : bz*INV_H2 + 256               */
#define BB1S_OFF  857    /* 96 f32 : bb1*INV_H + 256               */
/* total 953 words (<4KB) */

__device__ __forceinline__ uint32_t pack2(float a, float b) {
    h2 v = pkrtz(a, b);
    uint32_t u; __builtin_memcpy(&u, &v, 4); return u;
}

__global__ void prep_kernel(const float* __restrict__ A, const float* __restrict__ Bm,
                            const float* __restrict__ C, const float* __restrict__ Wz,
                            const float* __restrict__ bz, const float* __restrict__ W1,
                            const float* __restrict__ b1, const float* __restrict__ Wb1,
                            const float* __restrict__ bb1, const float* __restrict__ W2,
                            uint32_t* __restrict__ ws)
{
    const int tid = blockIdx.x * blockDim.x + threadIdx.x;
    const int nt = gridDim.x * blockDim.x;
    float* wsf = (float*)ws;

    for (int i = tid; i < 320; i += nt) {          // W1 pairs *INV_H (exact)
        int h = i / 5, j = i % 5;
        ws[W1P_OFF + i] = pack2(W1[h*10 + 2*j] * INV_H, W1[h*10 + 2*j + 1] * INV_H);
    }
    for (int i = tid; i < 35; i += nt) {           // Wz pairs *INV_H2 (exact)
        int r = i / 5, j = i % 5;
        ws[WZP_OFF + i] = pack2(Wz[r*10 + 2*j] * INV_H2, Wz[r*10 + 2*j + 1] * INV_H2);
    }
    for (int i = tid; i < 288; i += nt) {          // Wb1 pairs *INV_H (exact)
        int row = i / 3, j = i % 3;
        ws[WB1P_OFF + i] = pack2(Wb1[row*6 + 2*j] * INV_H, Wb1[row*6 + 2*j + 1] * INV_H);
    }
    for (int i = tid; i < 128; i += nt) {          // W2 h-pairs
        int k = i / 32, j = i % 32;
        ws[W2P_OFF + i] = pack2(W2[k*64 + 2*j], W2[k*64 + 2*j + 1]);
    }
    for (int i = tid; i < 9; i += nt) {            // (A|Bm) pairs vs bi=(s0,s1|s2,u0|u1,u2)
        int r = i / 3, j = i % 3;
        float a, b;
        if (j == 0) { a = A[r*3+0];  b = A[r*3+1];  }
        else if (j == 1) { a = A[r*3+2];  b = Bm[r*3+0]; }
        else { a = Bm[r*3+1]; b = Bm[r*3+2]; }
        ws[PHYSP_OFF + i] = pack2(a, b);
    }
    for (int i = tid; i < 6; i += nt) {            // C pairs (pad 0 vs u0)
        int r = i / 2, j = i % 2;
        float a = (j == 0) ? C[r*3+0] : C[r*3+2];
        float b = (j == 0) ? C[r*3+1] : 0.0f;
        ws[CP_OFF + i] = pack2(a, b);
    }
    for (int i = tid; i < 64; i += nt) wsf[B1S_OFF + i] = fmaf(b1[i], INV_H, TBL_C);
    for (int i = tid; i < 7;  i += nt) wsf[BZS_OFF + i] = fmaf(bz[i], INV_H2, TBL_C);
    for (int i = tid; i < 96; i += nt) wsf[BB1S_OFF + i] = fmaf(bb1[i], INV_H, TBL_C);
}

__global__ __launch_bounds__(256) void phygru_kernel(
    const float* __restrict__ state, const float* __restrict__ u,
    const uint32_t* __restrict__ ws, const float* __restrict__ b2,
    const float* __restrict__ Wb2,   const float* __restrict__ bb2,
    float* __restrict__ out)
{
    __shared__ float2 lut[512];
    {
        const int t0 = threadIdx.x;
        #pragma unroll
        for (int r = 0; r < 2; ++r) {
            int j = t0 + r * 256;
            float x  = (j - 256) * TBL_H;
            float v0 = tanh_ref(x);
            float v1 = tanh_ref(x + TBL_H);
            lut[j] = make_float2(v0, v1 - v0);
        }
    }
    __syncthreads();

    const int row = blockIdx.x * blockDim.x + threadIdx.x;

    const h2* W1p  = (const h2*)(ws + W1P_OFF);
    const h2* Wzp  = (const h2*)(ws + WZP_OFF);
    const h2* Wb1p = (const h2*)(ws + WB1P_OFF);
    const h2* W2p  = (const h2*)(ws + W2P_OFF);
    const h2* Pp   = (const h2*)(ws + PHYSP_OFF);
    const h2* Cp   = (const h2*)(ws + CP_OFF);
    const float* wsf  = (const float*)ws;
    const float* b1s  = wsf + B1S_OFF;
    const float* bzs  = wsf + BZS_OFF;
    const float* bb1s = wsf + BB1S_OFF;

    // ---- load row ----
    float st[7];
    #pragma unroll
    for (int i = 0; i < 7; ++i) st[i] = state[row * 7 + i];
    float uu[3];
    #pragma unroll
    for (int i = 0; i < 3; ++i) uu[i] = u[row * 3 + i];

    // packed su = [st(7), u(3)] as 5 half2; bi = [st(3), u(3)] as 3 half2
    h2 suh[5];
    suh[0] = pkrtz(st[0], st[1]);
    suh[1] = pkrtz(st[2], st[3]);
    suh[2] = pkrtz(st[4], st[5]);
    suh[3] = pkrtz(st[6], uu[0]);
    suh[4] = pkrtz(uu[1], uu[2]);
    h2 bih[3];
    bih[0] = suh[0];
    bih[1] = pkrtz(st[2], uu[0]);
    bih[2] = suh[4];

    // ---- physics ----
    float sp[3], yp[3];
    #pragma unroll
    for (int r = 0; r < 3; ++r) {
        float sd = fdot2(Pp[r*3+0], bih[0],
                   fdot2(Pp[r*3+1], bih[1],
                   fdot2(Pp[r*3+2], bih[2], 0.0f)));
        sp[r] = fmaf(DT_C, sd, st[r]);
        yp[r] = fdot2(Cp[r*2+0], bih[0], fdot2(Cp[r*2+1], bih[1], 0.0f));
    }

    // ---- latent MLP: tanh via LDS table (inputs pre-mapped to table units) ----
    float ld0 = b2[0], ld1 = b2[1], ld2 = b2[2], ld3 = b2[3];
    #pragma unroll
    for (int hp = 0; hp < 32; ++hp) {
        const int h0 = 2 * hp, h1 = 2 * hp + 1;
        float a0 = b1s[h0], a1 = b1s[h1];
        #pragma unroll
        for (int j = 0; j < 5; ++j) {
            a0 = fdot2(W1p[h0*5 + j], suh[j], a0);
            a1 = fdot2(W1p[h1*5 + j], suh[j], a1);
        }
        h2 th = pkrtz(tanh_lut(a0, lut), tanh_lut(a1, lut));
        ld0 = fdot2(W2p[0*32 + hp], th, ld0);
        ld1 = fdot2(W2p[1*32 + hp], th, ld1);
        ld2 = fdot2(W2p[2*32 + hp], th, ld2);
        ld3 = fdot2(W2p[3*32 + hp], th, ld3);
    }
    float ln[4];
    ln[0] = fmaf(DT_C, ld0, st[3]);
    ln[1] = fmaf(DT_C, ld1, st[4]);
    ln[2] = fmaf(DT_C, ld2, st[5]);
    ln[3] = fmaf(DT_C, ld3, st[6]);

    // ---- gate: z = 0.5 + 0.5*tanh(y/2), table units folded (*INV_H2) ----
    float ns[7];
    #pragma unroll
    for (int j = 0; j < 7; ++j) {
        float a = bzs[j];
        #pragma unroll
        for (int i = 0; i < 5; ++i) a = fdot2(Wzp[j*5 + i], suh[i], a);
        float z = fmaf(0.5f, tanh_lut(a, lut), 0.5f);
        float cand = (j < 3) ? sp[j] : ln[j - 3];
        ns[j] = fmaf(z, cand - st[j], st[j]);
    }

    // ---- branch residuals: tanh via LDS table ----
    float res[3];
    #pragma unroll
    for (int k = 0; k < 3; ++k) {
        float r = bb2[k];
        #pragma unroll
        for (int h = 0; h < 32; ++h) {
            float a = bb1s[k*32 + h];
            #pragma unroll
            for (int j = 0; j < 3; ++j)
                a = fdot2(Wb1p[(k*32 + h)*3 + j], bih[j], a);
            r = fmaf(Wb2[k*32 + h], tanh_lut(a, lut), r);
        }
        res[k] = r;
    }

    // ---- stores ----
    #pragma unroll
    for (int j = 0; j < 7; ++j) out[row * 7 + j] = ns[j];
    float* yout = out + (size_t)NROWS * 7;
    #pragma unroll
    for (int k = 0; k < 3; ++k) yout[row * 3 + k] = yp[k] + res[k];
}

extern "C" void kernel_launch(void* const* d_in, const int* in_sizes, int n_in,
                              void* d_out, int out_size, void* d_ws, size_t ws_size,
                              hipStream_t stream) {
    const float* state = (const float*)d_in[0];
    const float* u     = (const float*)d_in[1];
    const float* A     = (const float*)d_in[2];
    const float* Bm    = (const float*)d_in[3];
    const float* C     = (const float*)d_in[4];
    const float* Wz    = (const float*)d_in[5];
    const float* bz    = (const float*)d_in[6];
    const float* W1    = (const float*)d_in[7];
    const float* b1    = (const float*)d_in[8];
    const float* W2    = (const float*)d_in[9];
    const float* b2    = (const float*)d_in[10];
    const float* Wb1   = (const float*)d_in[11];
    const float* bb1   = (const float*)d_in[12];
    const float* Wb2   = (const float*)d_in[13];
    const float* bb2   = (const float*)d_in[14];
    float* out = (float*)d_out;
    uint32_t* ws = (uint32_t*)d_ws;

    prep_kernel<<<4, 256, 0, stream>>>(A, Bm, C, Wz, bz, W1, b1, Wb1, bb1, W2, ws);
    phygru_kernel<<<NROWS / 256, 256, 0, stream>>>(state, u, ws, b2, Wb2, bb2, out);
}